// Round 25
// baseline (49.475 us; speedup 1.0000x reference)
//
#include <hip/hip_runtime.h>
#include <hip/hip_bf16.h>
#include <stdint.h>

typedef __attribute__((ext_vector_type(8))) short bf16x8;
typedef __attribute__((ext_vector_type(16))) float f32x16;
using bf16 = __hip_bfloat16;

static constexpr int Mdim = 512;   // A batch
static constexpr int Ndim = 64;    // B batch
static constexpr int Cdim = 128;   // channels (K of the GEMM)
static constexpr int Pdim = 64;    // H*W positions
static constexpr float EPS_ADD = 0.001f;

// ---------------------------------------------------------------------------
// async global->LDS, 16B per lane
// ---------------------------------------------------------------------------
__device__ __forceinline__ void gll16(const void* gsrc, void* ldst) {
    const __attribute__((address_space(1))) unsigned int* g =
        (const __attribute__((address_space(1))) unsigned int*)gsrc;
    __attribute__((address_space(3))) unsigned int* l =
        (__attribute__((address_space(3))) unsigned int*)(uintptr_t)ldst;
    __builtin_amdgcn_global_load_lds(g, l, 16, 0, 0);
}

// ---------------------------------------------------------------------------
// prep (fused, UNCHANGED — verified): fragment-ordered outputs.
//   A-tile (per m): idx = h*4096 + ks*512 + lane*8 + e
//   G-tile (per n): idx = qt*4096 + ks*512 + lane*8 + e
// ---------------------------------------------------------------------------
__global__ void prep_kernel(const float* __restrict__ A, const float* __restrict__ B,
                            const float* __restrict__ Wg,
                            bf16* __restrict__ Afrag, bf16* __restrict__ Gfrag) {
    __shared__ float lds[128 * 65];
    const int t = threadIdx.x;

    if (blockIdx.x < 512) {
        const int m = blockIdx.x;
        const float* __restrict__ Am = A + (size_t)m * (Cdim * Pdim);
#pragma unroll
        for (int i = 0; i < 8; ++i) {
            int v = t + i * 256;
            int gidx = v * 4;
            int c = gidx >> 6, p = gidx & 63;
            float4 val = *reinterpret_cast<const float4*>(Am + gidx);
            float* dst = &lds[c * 65 + p];
            dst[0] = val.x; dst[1] = val.y; dst[2] = val.z; dst[3] = val.w;
        }
        __syncthreads();

        unsigned* __restrict__ dst32 = (unsigned*)(Afrag + (size_t)m * 8192);
#pragma unroll
        for (int i = 0; i < 16; ++i) {
            int pr = t + i * 256;
            int p = pr >> 6;
            int c = (pr & 63) << 1;
            float f0 = lds[c * 65 + p];
            float f1 = lds[(c + 1) * 65 + p];
            union { bf16 hh[2]; unsigned u; } pk;
            pk.hh[0] = __float2bfloat16(f0);
            pk.hh[1] = __float2bfloat16(f1);
            int h = p >> 5, l31 = p & 31;
            int ks = c >> 4, hi = (c >> 3) & 1, e = c & 7;
            dst32[h * 2048 + ks * 256 + hi * 128 + l31 * 4 + (e >> 1)] = pk.u;
        }
    } else {
        const int nb = blockIdx.x - 512;
        const int n  = nb >> 2;
        const int q0 = (nb & 3) * 16;
        const float* __restrict__ Bn = B + (size_t)n * (Cdim * Pdim);
#pragma unroll
        for (int i = 0; i < 8; ++i) {
            int v = t + i * 256;
            int gidx = v * 4;
            int c = gidx >> 6, q = gidx & 63;
            float4 val = *reinterpret_cast<const float4*>(Bn + gidx);
            float* dst = &lds[c * 65 + q];
            dst[0] = val.x; dst[1] = val.y; dst[2] = val.z; dst[3] = val.w;
        }
        __syncthreads();

        const int d  = t & 127;
        const int qb = q0 + (t >> 7) * 8;
        float acc[8] = {0.f, 0.f, 0.f, 0.f, 0.f, 0.f, 0.f, 0.f};
        for (int c = 0; c < 128; ++c) {
            float w = Wg[c * 128 + d];
#pragma unroll
            for (int qi = 0; qi < 8; ++qi)
                acc[qi] = fmaf(lds[c * 65 + qb + qi], w, acc[qi]);
        }
        bf16* __restrict__ gdst = Gfrag + (size_t)n * 8192;
        const int ks = d >> 4, hi = (d >> 3) & 1, e = d & 7;
#pragma unroll
        for (int qi = 0; qi < 8; ++qi) {
            int q = qb + qi;
            int qt = q >> 5, l31 = q & 31;
            gdst[qt * 4096 + ks * 512 + hi * 256 + l31 * 8 + e] = __float2bfloat16(acc[qi]);
        }
    }
}

// ---------------------------------------------------------------------------
// gemm_max v25: R=4 retry, allocator-friendly — the LDS-leg halving.
//  - Wave = 4 m-subs x one p-half: a0..a3 (named, static ks indexing) =
//    128 VGPR resident. One ds_read gf feeds 4 MFMA -> 256 B/MFMA (half of
//    v19's 512): per-CU LDS-read leg 24k -> 6k cyc, instr count 4x down.
//  - v19 shape otherwise: G (4 n's, 64KB) staged once; ONE vmcnt(0)+barrier
//    is the only sync; 4 free-running bodies {2 qt-phases of 8x(1 ds_read +
//    4 MFMA)}; online max over qt; v13's PROVEN store mapping.
//  - Anti-spill levers vs v13: __launch_bounds__(256,1) (512-reg headroom,
//    ~225 live -> still 2 waves/SIMD), named scalars/arrays only, no
//    array-capturing lambdas, single gf (compiler pipelines ds_reads).
//  - Block = 4 waves (mi,h) = 8 m's x 4 n's; grid 1024 = 16 bn x 64 mg;
//    bid%8 = mg%8 (same-A blocks on one XCD); LDS 64KB -> 2 blocks/CU.
// MFMA 32x32x16, mfma(G,A): D col = lane&31 = p, row = q (m74/m101).
// Spill tripwire: WRITE_SIZE must stay 8.19 MB.
// ---------------------------------------------------------------------------
__device__ __forceinline__ float red16(const f32x16& v) {
    float x0 = fmaxf(v[0], v[1]),  x1 = fmaxf(v[2], v[3]);
    float x2 = fmaxf(v[4], v[5]),  x3 = fmaxf(v[6], v[7]);
    float x4 = fmaxf(v[8], v[9]),  x5 = fmaxf(v[10], v[11]);
    float x6 = fmaxf(v[12], v[13]), x7 = fmaxf(v[14], v[15]);
    x0 = fmaxf(x0, x1); x2 = fmaxf(x2, x3);
    x4 = fmaxf(x4, x5); x6 = fmaxf(x6, x7);
    return fmaxf(fmaxf(x0, x2), fmaxf(x4, x6));
}

__global__ __launch_bounds__(256, 1)
void gemm_max_kernel(const bf16* __restrict__ Afrag, const bf16* __restrict__ Gfrag,
                     float* __restrict__ out) {
    __shared__ bf16 sG[4][8192];          // 64KB static, fragment order
    const int tid  = threadIdx.x;
    const int lane = tid & 63;
    const int wv   = tid >> 6;            // 0..3
    const int mi = wv >> 1, h = wv & 1;   // wave: m-quad index, p-half
    const int l31 = lane & 31, hi = lane >> 5;
    const int mg = blockIdx.x & 63;       // 64 m-groups of 8
    const int bn = blockIdx.x >> 6;       // 16 n-groups of 4
    const int m0 = mg * 8 + mi * 4;       // wave handles m0..m0+3

    // ---- A resident: 4 named frag arrays, 32 coalesced 1KB loads ----
    bf16x8 a0[8], a1[8], a2[8], a3[8];
    {
        const bf16* Ap = Afrag + (size_t)m0 * 8192 + h * 4096 + lane * 8;
#pragma unroll
        for (int ks = 0; ks < 8; ++ks) a0[ks] = *reinterpret_cast<const bf16x8*>(Ap + ks * 512);
#pragma unroll
        for (int ks = 0; ks < 8; ++ks) a1[ks] = *reinterpret_cast<const bf16x8*>(Ap + 8192 + ks * 512);
#pragma unroll
        for (int ks = 0; ks < 8; ++ks) a2[ks] = *reinterpret_cast<const bf16x8*>(Ap + 16384 + ks * 512);
#pragma unroll
        for (int ks = 0; ks < 8; ++ks) a3[ks] = *reinterpret_cast<const bf16x8*>(Ap + 24576 + ks * 512);
    }
    // ---- G stage: 64KB once ----
    {
        const char* Gsrc = (const char*)(Gfrag + (size_t)(bn * 4) * 8192);
#pragma unroll
        for (int i = 0; i < 16; ++i) {
            int f = (i * 256 + tid) * 16;
            gll16(Gsrc + f, (char*)sG + f);
        }
    }
    asm volatile("s_waitcnt vmcnt(0)" ::: "memory");
    __builtin_amdgcn_s_barrier();
    __builtin_amdgcn_sched_barrier(0);

    const f32x16 z16 = {0.f,0.f,0.f,0.f,0.f,0.f,0.f,0.f,0.f,0.f,0.f,0.f,0.f,0.f,0.f,0.f};

#pragma unroll
    for (int s = 0; s < 4; ++s) {
        const char* gb = (const char*)sG + s * 16384 + lane * 16;
        float r0, r1, r2, r3;
#pragma unroll
        for (int qt = 0; qt < 2; ++qt) {
            f32x16 acc0, acc1, acc2, acc3;
#pragma unroll
            for (int ks = 0; ks < 8; ++ks) {
                bf16x8 gf = *reinterpret_cast<const bf16x8*>(gb + qt * 8192 + ks * 1024);
                acc0 = __builtin_amdgcn_mfma_f32_32x32x16_bf16(gf, a0[ks], ks == 0 ? z16 : acc0, 0, 0, 0);
                acc1 = __builtin_amdgcn_mfma_f32_32x32x16_bf16(gf, a1[ks], ks == 0 ? z16 : acc1, 0, 0, 0);
                acc2 = __builtin_amdgcn_mfma_f32_32x32x16_bf16(gf, a2[ks], ks == 0 ? z16 : acc2, 0, 0, 0);
                acc3 = __builtin_amdgcn_mfma_f32_32x32x16_bf16(gf, a3[ks], ks == 0 ? z16 : acc3, 0, 0, 0);
            }
            float t0 = red16(acc0), t1 = red16(acc1);
            float t2 = red16(acc2), t3 = red16(acc3);
            if (qt == 0) { r0 = t0; r1 = t1; r2 = t2; r3 = t3; }
            else { r0 = fmaxf(r0, t0); r1 = fmaxf(r1, t1);
                   r2 = fmaxf(r2, t2); r3 = fmaxf(r3, t3); }
        }
        // fold q hi-halves (values become lane-replicated across hi)
        r0 = fmaxf(r0, __shfl_xor(r0, 32));
        r1 = fmaxf(r1, __shfl_xor(r1, 32));
        r2 = fmaxf(r2, __shfl_xor(r2, 32));
        r3 = fmaxf(r3, __shfl_xor(r3, 32));
        // v13's PROVEN mapping: lane (hi,l31) stores m-subs hi*2, hi*2+1
        const int n = bn * 4 + s;
        const float sa = hi ? r2 : r0;
        const float sb = hi ? r3 : r1;
        float* ob = out + (size_t)(m0 + hi * 2) * 4096 + n * 64 + h * 32 + l31;
        ob[0]    = fmaxf(sa, 0.f) + EPS_ADD;
        ob[4096] = fmaxf(sb, 0.f) + EPS_ADD;
    }
}

// ---------------------------------------------------------------------------
extern "C" void kernel_launch(void* const* d_in, const int* in_sizes, int n_in,
                              void* d_out, int out_size, void* d_ws, size_t ws_size,
                              hipStream_t stream) {
    const float* A  = (const float*)d_in[0];
    const float* B  = (const float*)d_in[1];
    const float* Wg = (const float*)d_in[2];
    float* out = (float*)d_out;

    bf16* Afrag = (bf16*)d_ws;                                      // 512 x 8192 bf16 = 8 MiB
    bf16* Gfrag = (bf16*)((char*)d_ws + (size_t)Mdim * Pdim * Cdim * sizeof(bf16)); // 64 x 8192 bf16

    prep_kernel<<<768, 256, 0, stream>>>(A, B, Wg, Afrag, Gfrag);
    gemm_max_kernel<<<1024, 256, 0, stream>>>(Afrag, Gfrag, out);   // 16 bn x 64 mg
}

// Round 26
// 45.101 us; speedup vs baseline: 1.0970x; 1.0970x over previous
//
#include <hip/hip_runtime.h>
#include <hip/hip_bf16.h>
#include <stdint.h>

typedef __attribute__((ext_vector_type(8))) short bf16x8;
typedef __attribute__((ext_vector_type(16))) float f32x16;
using bf16 = __hip_bfloat16;

static constexpr int Mdim = 512;   // A batch
static constexpr int Ndim = 64;    // B batch
static constexpr int Cdim = 128;   // channels (K of the GEMM)
static constexpr int Pdim = 64;    // H*W positions
static constexpr float EPS_ADD = 0.001f;

// ---------------------------------------------------------------------------
// async global->LDS, 16B per lane
// ---------------------------------------------------------------------------
__device__ __forceinline__ void gll16(const void* gsrc, void* ldst) {
    const __attribute__((address_space(1))) unsigned int* g =
        (const __attribute__((address_space(1))) unsigned int*)gsrc;
    __attribute__((address_space(3))) unsigned int* l =
        (__attribute__((address_space(3))) unsigned int*)(uintptr_t)ldst;
    __builtin_amdgcn_global_load_lds(g, l, 16, 0, 0);
}

// ---------------------------------------------------------------------------
// prep (fused, UNCHANGED — verified): fragment-ordered outputs.
//   A-tile (per m): idx = h*4096 + ks*512 + lane*8 + e
//   G-tile (per n): idx = qt*4096 + ks*512 + lane*8 + e
// ---------------------------------------------------------------------------
__global__ void prep_kernel(const float* __restrict__ A, const float* __restrict__ B,
                            const float* __restrict__ Wg,
                            bf16* __restrict__ Afrag, bf16* __restrict__ Gfrag) {
    __shared__ float lds[128 * 65];
    const int t = threadIdx.x;

    if (blockIdx.x < 512) {
        const int m = blockIdx.x;
        const float* __restrict__ Am = A + (size_t)m * (Cdim * Pdim);
#pragma unroll
        for (int i = 0; i < 8; ++i) {
            int v = t + i * 256;
            int gidx = v * 4;
            int c = gidx >> 6, p = gidx & 63;
            float4 val = *reinterpret_cast<const float4*>(Am + gidx);
            float* dst = &lds[c * 65 + p];
            dst[0] = val.x; dst[1] = val.y; dst[2] = val.z; dst[3] = val.w;
        }
        __syncthreads();

        unsigned* __restrict__ dst32 = (unsigned*)(Afrag + (size_t)m * 8192);
#pragma unroll
        for (int i = 0; i < 16; ++i) {
            int pr = t + i * 256;
            int p = pr >> 6;
            int c = (pr & 63) << 1;
            float f0 = lds[c * 65 + p];
            float f1 = lds[(c + 1) * 65 + p];
            union { bf16 hh[2]; unsigned u; } pk;
            pk.hh[0] = __float2bfloat16(f0);
            pk.hh[1] = __float2bfloat16(f1);
            int h = p >> 5, l31 = p & 31;
            int ks = c >> 4, hi = (c >> 3) & 1, e = c & 7;
            dst32[h * 2048 + ks * 256 + hi * 128 + l31 * 4 + (e >> 1)] = pk.u;
        }
    } else {
        const int nb = blockIdx.x - 512;
        const int n  = nb >> 2;
        const int q0 = (nb & 3) * 16;
        const float* __restrict__ Bn = B + (size_t)n * (Cdim * Pdim);
#pragma unroll
        for (int i = 0; i < 8; ++i) {
            int v = t + i * 256;
            int gidx = v * 4;
            int c = gidx >> 6, q = gidx & 63;
            float4 val = *reinterpret_cast<const float4*>(Bn + gidx);
            float* dst = &lds[c * 65 + q];
            dst[0] = val.x; dst[1] = val.y; dst[2] = val.z; dst[3] = val.w;
        }
        __syncthreads();

        const int d  = t & 127;
        const int qb = q0 + (t >> 7) * 8;
        float acc[8] = {0.f, 0.f, 0.f, 0.f, 0.f, 0.f, 0.f, 0.f};
        for (int c = 0; c < 128; ++c) {
            float w = Wg[c * 128 + d];
#pragma unroll
            for (int qi = 0; qi < 8; ++qi)
                acc[qi] = fmaf(lds[c * 65 + qb + qi], w, acc[qi]);
        }
        bf16* __restrict__ gdst = Gfrag + (size_t)n * 8192;
        const int ks = d >> 4, hi = (d >> 3) & 1, e = d & 7;
#pragma unroll
        for (int qi = 0; qi < 8; ++qi) {
            int q = qb + qi;
            int qt = q >> 5, l31 = q & 31;
            gdst[qt * 4096 + ks * 512 + hi * 256 + l31 * 8 + e] = __float2bfloat16(acc[qi]);
        }
    }
}

// ---------------------------------------------------------------------------
// gemm_max v26: v25 byte-identical EXCEPT __launch_bounds__(256,2).
// Tests the precise hypothesis that v25's regression was residency (1
// block/CU at (256,1)), not R=4 itself. R=4 halves the LDS-read leg
// (524k -> 262k ds_read_b128) and halves G-stage traffic (128 -> 64 MB);
// leg-sum model predicts gemm ~34us IF 2 blocks/CU go resident.
//  - Wave = 4 m-subs x one p-half: a0..a3 named arrays (128 VGPR resident);
//    one ds_read gf feeds 4 MFMA -> 256 B/MFMA.
//  - G (4 n's, 64KB) staged once; ONE vmcnt(0)+barrier = only sync.
//  - 4 free-running bodies {2 qt-phases of 8x(1 ds_read + 4 MFMA)};
//    online max over qt; v13's proven store mapping.
//  - Grid 1024 = 16 bn x 64 mg; bid%8 = mg%8; LDS 64KB -> 2 blocks/CU.
// Spill tripwire: WRITE_SIZE must stay 8.19 MB (v13's (256,2) spilled with
// array-of-array code; v25's named-array code compiled clean at 184).
// MFMA 32x32x16, mfma(G,A): D col = lane&31 = p, row = q (m74/m101).
// ---------------------------------------------------------------------------
__device__ __forceinline__ float red16(const f32x16& v) {
    float x0 = fmaxf(v[0], v[1]),  x1 = fmaxf(v[2], v[3]);
    float x2 = fmaxf(v[4], v[5]),  x3 = fmaxf(v[6], v[7]);
    float x4 = fmaxf(v[8], v[9]),  x5 = fmaxf(v[10], v[11]);
    float x6 = fmaxf(v[12], v[13]), x7 = fmaxf(v[14], v[15]);
    x0 = fmaxf(x0, x1); x2 = fmaxf(x2, x3);
    x4 = fmaxf(x4, x5); x6 = fmaxf(x6, x7);
    return fmaxf(fmaxf(x0, x2), fmaxf(x4, x6));
}

__global__ __launch_bounds__(256, 2)
void gemm_max_kernel(const bf16* __restrict__ Afrag, const bf16* __restrict__ Gfrag,
                     float* __restrict__ out) {
    __shared__ bf16 sG[4][8192];          // 64KB static, fragment order
    const int tid  = threadIdx.x;
    const int lane = tid & 63;
    const int wv   = tid >> 6;            // 0..3
    const int mi = wv >> 1, h = wv & 1;   // wave: m-quad index, p-half
    const int l31 = lane & 31, hi = lane >> 5;
    const int mg = blockIdx.x & 63;       // 64 m-groups of 8
    const int bn = blockIdx.x >> 6;       // 16 n-groups of 4
    const int m0 = mg * 8 + mi * 4;       // wave handles m0..m0+3

    // ---- A resident: 4 named frag arrays, 32 coalesced 1KB loads ----
    bf16x8 a0[8], a1[8], a2[8], a3[8];
    {
        const bf16* Ap = Afrag + (size_t)m0 * 8192 + h * 4096 + lane * 8;
#pragma unroll
        for (int ks = 0; ks < 8; ++ks) a0[ks] = *reinterpret_cast<const bf16x8*>(Ap + ks * 512);
#pragma unroll
        for (int ks = 0; ks < 8; ++ks) a1[ks] = *reinterpret_cast<const bf16x8*>(Ap + 8192 + ks * 512);
#pragma unroll
        for (int ks = 0; ks < 8; ++ks) a2[ks] = *reinterpret_cast<const bf16x8*>(Ap + 16384 + ks * 512);
#pragma unroll
        for (int ks = 0; ks < 8; ++ks) a3[ks] = *reinterpret_cast<const bf16x8*>(Ap + 24576 + ks * 512);
    }
    // ---- G stage: 64KB once ----
    {
        const char* Gsrc = (const char*)(Gfrag + (size_t)(bn * 4) * 8192);
#pragma unroll
        for (int i = 0; i < 16; ++i) {
            int f = (i * 256 + tid) * 16;
            gll16(Gsrc + f, (char*)sG + f);
        }
    }
    asm volatile("s_waitcnt vmcnt(0)" ::: "memory");
    __builtin_amdgcn_s_barrier();
    __builtin_amdgcn_sched_barrier(0);

    const f32x16 z16 = {0.f,0.f,0.f,0.f,0.f,0.f,0.f,0.f,0.f,0.f,0.f,0.f,0.f,0.f,0.f,0.f};

#pragma unroll
    for (int s = 0; s < 4; ++s) {
        const char* gb = (const char*)sG + s * 16384 + lane * 16;
        float r0, r1, r2, r3;
#pragma unroll
        for (int qt = 0; qt < 2; ++qt) {
            f32x16 acc0, acc1, acc2, acc3;
#pragma unroll
            for (int ks = 0; ks < 8; ++ks) {
                bf16x8 gf = *reinterpret_cast<const bf16x8*>(gb + qt * 8192 + ks * 1024);
                acc0 = __builtin_amdgcn_mfma_f32_32x32x16_bf16(gf, a0[ks], ks == 0 ? z16 : acc0, 0, 0, 0);
                acc1 = __builtin_amdgcn_mfma_f32_32x32x16_bf16(gf, a1[ks], ks == 0 ? z16 : acc1, 0, 0, 0);
                acc2 = __builtin_amdgcn_mfma_f32_32x32x16_bf16(gf, a2[ks], ks == 0 ? z16 : acc2, 0, 0, 0);
                acc3 = __builtin_amdgcn_mfma_f32_32x32x16_bf16(gf, a3[ks], ks == 0 ? z16 : acc3, 0, 0, 0);
            }
            float t0 = red16(acc0), t1 = red16(acc1);
            float t2 = red16(acc2), t3 = red16(acc3);
            if (qt == 0) { r0 = t0; r1 = t1; r2 = t2; r3 = t3; }
            else { r0 = fmaxf(r0, t0); r1 = fmaxf(r1, t1);
                   r2 = fmaxf(r2, t2); r3 = fmaxf(r3, t3); }
        }
        // fold q hi-halves (values become lane-replicated across hi)
        r0 = fmaxf(r0, __shfl_xor(r0, 32));
        r1 = fmaxf(r1, __shfl_xor(r1, 32));
        r2 = fmaxf(r2, __shfl_xor(r2, 32));
        r3 = fmaxf(r3, __shfl_xor(r3, 32));
        // v13's PROVEN mapping: lane (hi,l31) stores m-subs hi*2, hi*2+1
        const int n = bn * 4 + s;
        const float sa = hi ? r2 : r0;
        const float sb = hi ? r3 : r1;
        float* ob = out + (size_t)(m0 + hi * 2) * 4096 + n * 64 + h * 32 + l31;
        ob[0]    = fmaxf(sa, 0.f) + EPS_ADD;
        ob[4096] = fmaxf(sb, 0.f) + EPS_ADD;
    }
}

// ---------------------------------------------------------------------------
extern "C" void kernel_launch(void* const* d_in, const int* in_sizes, int n_in,
                              void* d_out, int out_size, void* d_ws, size_t ws_size,
                              hipStream_t stream) {
    const float* A  = (const float*)d_in[0];
    const float* B  = (const float*)d_in[1];
    const float* Wg = (const float*)d_in[2];
    float* out = (float*)d_out;

    bf16* Afrag = (bf16*)d_ws;                                      // 512 x 8192 bf16 = 8 MiB
    bf16* Gfrag = (bf16*)((char*)d_ws + (size_t)Mdim * Pdim * Cdim * sizeof(bf16)); // 64 x 8192 bf16

    prep_kernel<<<768, 256, 0, stream>>>(A, B, Wg, Afrag, Gfrag);
    gemm_max_kernel<<<1024, 256, 0, stream>>>(Afrag, Gfrag, out);   // 16 bn x 64 mg
}